// Round 17
// baseline (581.853 us; speedup 1.0000x reference)
//
#include <hip/hip_runtime.h>

#define Bq 2
#define Yq 512
#define Xq 512
#define NVOX 400000

typedef __bf16 bf16x8 __attribute__((ext_vector_type(8)));
typedef float f32x4 __attribute__((ext_vector_type(4)));
typedef float f32x16 __attribute__((ext_vector_type(16)));
typedef short s16x8 __attribute__((ext_vector_type(8)));

__device__ __forceinline__ short f2bf_s(float f){
    return __builtin_bit_cast(short, static_cast<__bf16>(f));
}
__device__ __forceinline__ float bfbits2f(unsigned u){
    unsigned v = u << 16; return __builtin_bit_cast(float, v);
}

// ---------------- weight transpose + bf16 convert ----------------
// wTs[tap][cout][slot]: PRE-SWIZZLED for LDS (see kconv).
// wpT[cout][cin] <- W_proj[cin][cout]
__global__ void kprep(const float* __restrict__ conv_w, const float* __restrict__ W_proj,
                      short* __restrict__ wTs, short* __restrict__ wpT){
    int tid = blockIdx.x*256 + threadIdx.x;
    if (tid < 9*128*128){
        int tap = tid >> 14; int r = tid & 16383; int co = r >> 7; int ci = r & 127;
        int g = ci >> 3, e = ci & 7;
        wTs[tap*16384 + co*128 + (((g & 8) | ((g & 7) ^ (co & 7))) << 3) + e] =
            f2bf_s(conv_w[tap*16384 + ci*128 + co]);
    }
    int e = tid - 9*128*128;
    if (e >= 0 && e < 128*192){
        int co = e / 192; int ci = e - co*192;
        wpT[e] = f2bf_s(W_proj[ci*128 + co]);
    }
}

// ---------------- per-cell count + RANK + active mask ----------------
__global__ void kcount(const int* __restrict__ vc, unsigned* __restrict__ cnt,
                       unsigned* __restrict__ vrank, unsigned char* __restrict__ act){
    int i = blockIdx.x*256 + threadIdx.x;
    if (i >= NVOX) return;
    const int4 c = *reinterpret_cast<const int4*>(vc + i*4);
    int cell = (c.x*Yq + c.z)*Xq + c.w;
    act[cell] = 1;
    vrank[i] = atomicAdd(&cnt[cell], 1u);
}

// ---------------- slot allocation: WAVE-AGGREGATED (G12 fix) ----------------
// 64-lane inclusive scan of (c-1) and multi-flag; ONE atomic pair per wave.
__global__ void kalloc(const unsigned* __restrict__ cnt, unsigned* __restrict__ base,
                       unsigned* __restrict__ mlist, unsigned* __restrict__ ctr){
    int cell = blockIdx.x*256 + threadIdx.x;
    const int lane = threadIdx.x & 63;
    unsigned c = (cell < Bq*Yq*Xq) ? cnt[cell] : 0u;
    unsigned excess = (c > 1) ? (c - 1) : 0u;
    unsigned ism    = (c > 1) ? 1u : 0u;
    unsigned se = excess, si = ism;           // inclusive scans
    #pragma unroll
    for (int d = 1; d < 64; d <<= 1){
        unsigned te = __shfl_up(se, d);
        unsigned ti = __shfl_up(si, d);
        if (lane >= d){ se += te; si += ti; }
    }
    unsigned totE = __shfl(se, 63), totI = __shfl(si, 63);
    unsigned bE = 0, bI = 0;
    if (lane == 63 && (totE | totI)){
        bE = atomicAdd(&ctr[0], totE);
        bI = atomicAdd(&ctr[1], totI);
    }
    bE = __shfl(bE, 63); bI = __shfl(bI, 63);
    if (c > 1){
        base[cell]        = bE + se - excess;   // exclusive prefix
        mlist[bI + si - 1] = (unsigned)cell;
    }
}

// ---------------- projection + BN1 + ReLU + ATOMIC-FREE scatter ----------
// rank-0 / singleton voxels: plain full-line store into dbf (sole writer).
// rank>0 voxels: plain coalesced store into compact scratch slot.
__global__ void __launch_bounds__(256, 4)
kproj(const float* __restrict__ vf, const int* __restrict__ vc,
      const unsigned* __restrict__ cnt, const unsigned* __restrict__ vrank,
      const unsigned* __restrict__ base,
      const short* __restrict__ wpT, const float* __restrict__ bp,
      const float* __restrict__ g1, const float* __restrict__ be1,
      const float* __restrict__ mu1, const float* __restrict__ va1,
      short* __restrict__ dbf, unsigned* __restrict__ scratch){
    __shared__ char smem[64*200*2];     // A (bf16 stage) ∪ st (u32 pairs)
    __shared__ int cellsPk[64];         // (scratch<<30) | P*8 + (xp&7)
    __shared__ int slotArr[64];
    short*    A  = (short*)smem;
    unsigned* st = (unsigned*)smem;     // st[vx*68 + j]
    const int t = threadIdx.x;
    const int v0 = blockIdx.x * 64;

    const float4* vf4 = reinterpret_cast<const float4*>(vf);
    #pragma unroll
    for (int j = 0; j < 12; ++j){
        int i = t + j*256;
        int v = i / 48, kq = i - v*48;
        float4 x = vf4[(size_t)(v0 + v)*48 + kq];
        short4 s; s.x=f2bf_s(x.x); s.y=f2bf_s(x.y); s.z=f2bf_s(x.z); s.w=f2bf_s(x.w);
        *reinterpret_cast<short4*>(&A[v*200 + kq*4]) = s;
    }
    if (t < 64){
        int vi = v0 + t;
        int bi = vc[vi*4 + 0], yi = vc[vi*4 + 2], xi = vc[vi*4 + 3];
        int cell = (bi*Yq + yi)*Xq + xi;
        unsigned cn = cnt[cell];
        unsigned rk = vrank[vi];
        int P = (bi*514 + (yi + 1))*514 + (xi + 1);
        int toScratch = (cn > 1 && rk > 0) ? 1 : 0;
        cellsPk[t] = (P*8 + ((xi + 1) & 7)) | (toScratch << 30);
        slotArr[t] = toScratch ? (int)(base[cell] + rk - 1) : 0;
    }
    __syncthreads();

    const int w  = t >> 6;
    const int l  = t & 63;
    const int lr = l & 15;
    const int q  = l >> 4;

    const short* wp_lane = wpT + (size_t)(w*32 + lr)*192 + q*8;
    bf16x8 bb[2][6];
    #pragma unroll
    for (int n = 0; n < 2; ++n)
        #pragma unroll
        for (int kc = 0; kc < 6; ++kc)
            bb[n][kc] = *reinterpret_cast<const bf16x8*>(wp_lane + n*16*192 + kc*32);

    f32x4 acc[4][2] = {};
    #pragma unroll
    for (int kc = 0; kc < 6; ++kc){
        bf16x8 a[4];
        #pragma unroll
        for (int m = 0; m < 4; ++m)
            a[m] = *reinterpret_cast<const bf16x8*>(&A[(m*16 + lr)*200 + kc*32 + q*8]);
        #pragma unroll
        for (int m = 0; m < 4; ++m)
            #pragma unroll
            for (int n = 0; n < 2; ++n)
                acc[m][n] = __builtin_amdgcn_mfma_f32_16x16x32_bf16(a[m], bb[n][kc], acc[m][n], 0, 0, 0);
    }

    __syncthreads();                    // A reads done; smem becomes st
    const int odd = lr & 1;
    #pragma unroll
    for (int n = 0; n < 2; ++n){
        int c = w*32 + n*16 + lr;
        float s1  = g1[c] * rsqrtf(va1[c] + 1e-5f);
        float sh1 = be1[c] + (bp[c] - mu1[c]) * s1;
        int jj = w*16 + n*8 + (lr >> 1);
        #pragma unroll
        for (int m = 0; m < 4; ++m){
            #pragma unroll
            for (int r = 0; r < 4; ++r){
                int vx = m*16 + q*4 + r;
                float val = fmaxf(fmaf(acc[m][n][r], s1, sh1), 0.f);
                float vp  = __shfl_xor(val, 1);
                if (!odd){
                    unsigned data = (unsigned)(unsigned short)f2bf_s(val)
                                  | ((unsigned)(unsigned short)f2bf_s(vp) << 16);
                    st[vx*68 + jj] = data;
                }
            }
        }
    }
    __syncthreads();

    // scatter: wave w handles voxels w*16..w*16+15; lane l writes pair l.
    // All plain stores — no atomics.
    unsigned* dbf_u32 = reinterpret_cast<unsigned*>(dbf);
    #pragma unroll
    for (int i = 0; i < 16; ++i){
        int vv = w*16 + i;
        int pk = cellsPk[vv];
        unsigned data = st[vv*68 + l];
        if (pk >> 30){
            scratch[(size_t)slotArr[vv]*64 + l] = data;
        } else {
            int P = (pk & 0x3fffffff) >> 3, xp7 = pk & 7;
            dbf_u32[(size_t)P*64 + (((l >> 2) ^ xp7) << 2) + (l & 3)] = data;
        }
    }
}

// ---------------- multi-cell fix-up: f32 sum of rank lines ----------------
__global__ void __launch_bounds__(256)
kfix(const unsigned* __restrict__ mlist, const unsigned* __restrict__ ctr,
     const unsigned* __restrict__ cnt, const unsigned* __restrict__ base,
     const unsigned* __restrict__ scratch, unsigned* __restrict__ dbf_u32){
    const unsigned nM = ctr[1];
    const int l = threadIdx.x & 63;
    const unsigned wid = (blockIdx.x*256 + threadIdx.x) >> 6;
    const unsigned nw = gridDim.x * 4;
    for (unsigned i = wid; i < nM; i += nw){
        unsigned cell = mlist[i];
        int x  = cell & 511;
        int by = cell >> 9;            // b*512 + y
        int b  = by >> 9, y = by & 511;
        int P  = (b*514 + y + 1)*514 + (x + 1);
        int xp7 = (x + 1) & 7;
        unsigned c  = cnt[cell];
        unsigned bs = base[cell];
        size_t didx = (size_t)P*64 + (((l >> 2) ^ xp7) << 2) + (l & 3);
        unsigned d = dbf_u32[didx];
        float lo = bfbits2f(d & 0xffff), hi = bfbits2f(d >> 16);
        for (unsigned r = 0; r + 1 < c; ++r){
            unsigned s = scratch[(size_t)(bs + r)*64 + l];
            lo += bfbits2f(s & 0xffff);
            hi += bfbits2f(s >> 16);
        }
        dbf_u32[didx] = (unsigned)(unsigned short)f2bf_s(lo)
                      | ((unsigned)(unsigned short)f2bf_s(hi) << 16);
    }
}

// ---------------- conv 3x3 + BN2 + ReLU + mask (R10 champion, verbatim) ----
__global__ void __launch_bounds__(512, 2)
kconv(const short* __restrict__ dbf, const short* __restrict__ wTs,
      const unsigned char* __restrict__ act, const float* __restrict__ cb,
      const float* __restrict__ g2, const float* __restrict__ be2,
      const float* __restrict__ mu2, const float* __restrict__ va2,
      float* __restrict__ out){
    __shared__ short Atile[5*1056*8];    // 84,480 B
    __shared__ short Bbuf[4][1024*8];    // 4 x 16,384 B   (total 150,016 B)
    const int t = threadIdx.x;
    const int bid = (blockIdx.x & 7)*256 + (blockIdx.x >> 3);
    const int b   = bid >> 10;
    const int rem = bid & 1023;
    const int y0  = (rem >> 3) << 2;
    const int x0  = (rem & 7) << 6;

    const int w   = t >> 6, l = t & 63;
    const int yy  = w >> 1, nn = w & 1;
    const int l31 = l & 31, hi = l >> 5;
    const int wbase16 = w*64*16;

    #define STAGE_B(BUF, H) do {                                              \
        const short* gb = wTs + (size_t)((H) >> 1)*16384 + ((H) & 1)*64;      \
        _Pragma("unroll")                                                     \
        for (int j = 0; j < 2; ++j){                                          \
            int S = j*512 + t;                                                \
            const short* gp = gb + (S >> 3)*128 + (S & 7)*8;                  \
            __builtin_amdgcn_global_load_lds(                                 \
                (const __attribute__((address_space(1))) void*)gp,            \
                (__attribute__((address_space(3))) void*)                    \
                    ((char*)Bbuf[BUF] + (size_t)(j*512*16) + wbase16), 16, 0, 0); \
        }                                                                     \
    } while(0)

    STAGE_B(0, 0);
    STAGE_B(1, 1);
    #pragma unroll
    for (int j = 0; j < 11; ++j){
        int S = j*512 + t;
        if (S < 5280){
            int r = S / 1056, s = S - r*1056;
            const short* gp = dbf + ((size_t)((b*514 + (y0 + r))*514 + x0)*16 + s)*8;
            __builtin_amdgcn_global_load_lds(
                (const __attribute__((address_space(1))) void*)gp,
                (__attribute__((address_space(3))) void*)
                    ((char*)Atile + (size_t)(j*512*16) + wbase16), 16, 0, 0);
        }
    }

    f32x16 acc[2][2] = {};
    const int bReadBase = (nn*64 + l31)*64;
    const int bXor = l31 & 7;

    #pragma unroll
    for (int p = 0; p < 18; ++p){
        if ((p & 1) == 0){
            __builtin_amdgcn_sched_barrier(0);
            asm volatile("s_waitcnt vmcnt(0)" ::: "memory");
            __builtin_amdgcn_s_barrier();
            __builtin_amdgcn_sched_barrier(0);
            if (p + 2 < 18) STAGE_B((p+2) & 3, p+2);
            if (p + 3 < 18) STAGE_B((p+3) & 3, p+3);
            if (p == 6){
                #pragma unroll
                for (int j = 0; j < 3; ++j){
                    int S = j*512 + t;
                    if (S < 1056){
                        const short* gp = dbf + ((size_t)((b*514 + (y0 + 5))*514 + x0)*16 + S)*8;
                        __builtin_amdgcn_global_load_lds(
                            (const __attribute__((address_space(1))) void*)gp,
                            (__attribute__((address_space(3))) void*)
                                ((char*)Atile + (size_t)(j*512 + w*64)*16), 16, 0, 0);
                    }
                }
            }
            __builtin_amdgcn_sched_barrier(0);
        }
        const short* Bc = Bbuf[p & 3];
        const int tap = p >> 1, hh = p & 1;
        const int ky = tap / 3, kx = tap - ky*3;
        const int row = yy + ky;
        const int rowp = (row >= 5) ? 0 : row;       // 5-row rotation
        const int p0 = l31 + kx, p1 = p0 + 32;
        const int base0 = (rowp*1056 + p0*16)*8;
        const int base1 = (rowp*1056 + p1*16)*8;
        const int pk7 = p0 & 7;
        #pragma unroll
        for (int kc = 0; kc < 4; ++kc){
            const int ks  = kc*2 + hi;
            const int q   = ((hh*8 + ks) ^ pk7) << 3;
            const int qb  = (ks ^ bXor) << 3;
            bf16x8 a0 = *reinterpret_cast<const bf16x8*>(&Atile[base0 + q]);
            bf16x8 a1 = *reinterpret_cast<const bf16x8*>(&Atile[base1 + q]);
            bf16x8 b0 = *reinterpret_cast<const bf16x8*>(&Bc[bReadBase + qb]);
            bf16x8 b1 = *reinterpret_cast<const bf16x8*>(&Bc[bReadBase + 2048 + qb]);
            acc[0][0] = __builtin_amdgcn_mfma_f32_32x32x16_bf16(a0, b0, acc[0][0], 0, 0, 0);
            acc[0][1] = __builtin_amdgcn_mfma_f32_32x32x16_bf16(a0, b1, acc[0][1], 0, 0, 0);
            acc[1][0] = __builtin_amdgcn_mfma_f32_32x32x16_bf16(a1, b0, acc[1][0], 0, 0, 0);
            acc[1][1] = __builtin_amdgcn_mfma_f32_32x32x16_bf16(a1, b1, acc[1][1], 0, 0, 0);
        }
    }
    #undef STAGE_B

    const int yg = y0 + yy;
    const size_t rowcell = (size_t)(b*Yq + yg)*Xq + x0;
    #pragma unroll
    for (int ni = 0; ni < 2; ++ni){
        int c = nn*64 + ni*32 + l31;
        float s2  = g2[c] * rsqrtf(va2[c] + 1e-3f);
        float sh2 = be2[c] + (cb[c] - mu2[c]) * s2;
        #pragma unroll
        for (int mi = 0; mi < 2; ++mi){
            #pragma unroll
            for (int r = 0; r < 16; ++r){
                int pos = mi*32 + (r & 3) + ((r >> 2) << 3) + hi*4;
                size_t cell = rowcell + pos;
                float v = act[cell] ? fmaxf(fmaf(acc[mi][ni][r], s2, sh2), 0.f) : 0.f;
                out[cell*128 + c] = v;
            }
        }
    }
}

extern "C" void kernel_launch(void* const* d_in, const int* in_sizes, int n_in,
                              void* d_out, int out_size, void* d_ws, size_t ws_size,
                              hipStream_t stream){
    const float* vf  = (const float*)d_in[0];
    const int*   vc  = (const int*)  d_in[1];
    const float* Wp  = (const float*)d_in[2];
    const float* bp  = (const float*)d_in[3];
    const float* g1  = (const float*)d_in[4];
    const float* be1 = (const float*)d_in[5];
    const float* mu1 = (const float*)d_in[6];
    const float* va1 = (const float*)d_in[7];
    const float* cw  = (const float*)d_in[8];
    const float* cb  = (const float*)d_in[9];
    const float* g2  = (const float*)d_in[10];
    const float* be2 = (const float*)d_in[11];
    const float* mu2 = (const float*)d_in[12];
    const float* va2 = (const float*)d_in[13];
    float* out = (float*)d_out;
    char* ws = (char*)d_ws;

    // ws layout (bytes):
    //   dbf bf16 [2][514][514][128] : 135,268,352 @ 0   (padded, pre-swizzled)
    //   act  u8  [2][512][512]      :     524,288 @ 135,268,352
    //   wTs  bf16 [9][128][128]     :     294,912 @ 135,792,640  (pre-swizzled)
    //   wpT  bf16 [128][192]        :      49,152 @ 136,087,552
    //   cnt  u32 [2][512][512]      :   2,097,152 @ 136,136,704
    //   vrank u32 [400000]          :   1,600,000 @ 138,233,856
    //   base u32 [2][512][512]      :   2,097,152 @ 139,833,856
    //   mlist u32 [2*512*512]       :   2,097,152 @ 141,931,008
    //   ctr  u32 [64]               :         256 @ 144,028,160
    //   scratch u32 [400000][64]    : 102,400,000 @ 144,028,416  (end 246,428,416)
    if (ws_size < 246428416ull) return;
    short* dbf = (short*)ws;
    unsigned char* act = (unsigned char*)(ws + 135268352);
    short* wTs = (short*)(ws + 135792640);
    short* wpT = (short*)(ws + 136087552);
    unsigned* cnt   = (unsigned*)(ws + 136136704);
    unsigned* vrank = (unsigned*)(ws + 138233856);
    unsigned* base  = (unsigned*)(ws + 139833856);
    unsigned* mlist = (unsigned*)(ws + 141931008);
    unsigned* ctr   = (unsigned*)(ws + 144028160);
    unsigned* scratch = (unsigned*)(ws + 144028416);

    hipMemsetAsync(dbf, 0, 135268352, stream);
    hipMemsetAsync(act, 0, 524288, stream);
    hipMemsetAsync(cnt, 0, 2097152, stream);
    hipMemsetAsync(ctr, 0, 256, stream);
    kprep<<<672, 256, 0, stream>>>(cw, Wp, wTs, wpT);
    kcount<<<1563, 256, 0, stream>>>(vc, cnt, vrank, act);
    kalloc<<<2048, 256, 0, stream>>>(cnt, base, mlist, ctr);
    kproj<<<6250, 256, 0, stream>>>(vf, vc, cnt, vrank, base, wpT, bp,
                                    g1, be1, mu1, va1, dbf, scratch);
    kfix<<<2048, 256, 0, stream>>>(mlist, ctr, cnt, base, scratch,
                                   (unsigned*)dbf);
    kconv<<<2048, 512, 0, stream>>>(dbf, wTs, act, cb, g2, be2, mu2, va2, out);
}

// Round 18
// 358.274 us; speedup vs baseline: 1.6240x; 1.6240x over previous
//
#include <hip/hip_runtime.h>

#define Bq 2
#define Yq 512
#define Xq 512
#define NVOX 400000

typedef __bf16 bf16x8 __attribute__((ext_vector_type(8)));
typedef float f32x4 __attribute__((ext_vector_type(4)));
typedef float f32x16 __attribute__((ext_vector_type(16)));
typedef short s16x8 __attribute__((ext_vector_type(8)));
typedef short s16x2 __attribute__((ext_vector_type(2)));

__device__ __forceinline__ short f2bf_s(float f){
    return __builtin_bit_cast(short, static_cast<__bf16>(f));
}
__device__ __forceinline__ float bfbits2f(unsigned short u){
    unsigned v = ((unsigned)u) << 16; return __builtin_bit_cast(float, v);
}

__device__ __forceinline__ void atomic_pk_add_bf16(short* addr, unsigned data){
#if __has_builtin(__builtin_amdgcn_global_atomic_fadd_v2bf16)
    s16x2 v; v[0] = (short)(data & 0xffff); v[1] = (short)(data >> 16);
    __builtin_amdgcn_global_atomic_fadd_v2bf16(
        (__attribute__((address_space(1))) s16x2*)addr, v);
#else
    asm volatile("global_atomic_pk_add_bf16 %0, %1, off"
                 :: "v"(addr), "v"(data) : "memory");
#endif
}

// ---------------- weight transpose + bf16 convert ----------------
// wTs[tap][cout][slot]: PRE-SWIZZLED for LDS — cin-group g of cout stored at
// slot (g&8) | ((g&7) ^ (cout&7)); linear global_load_lds then gives
// conflict-free ds_read_b128 in kconv.
// wpT[cout][cin] <- W_proj[cin][cout]
__global__ void kprep(const float* __restrict__ conv_w, const float* __restrict__ W_proj,
                      short* __restrict__ wTs, short* __restrict__ wpT){
    int tid = blockIdx.x*256 + threadIdx.x;
    if (tid < 9*128*128){
        int tap = tid >> 14; int r = tid & 16383; int co = r >> 7; int ci = r & 127;
        int g = ci >> 3, e = ci & 7;
        wTs[tap*16384 + co*128 + (((g & 8) | ((g & 7) ^ (co & 7))) << 3) + e] =
            f2bf_s(conv_w[tap*16384 + ci*128 + co]);
    }
    int e = tid - 9*128*128;
    if (e >= 0 && e < 128*192){
        int co = e / 192; int ci = e - co*192;
        wpT[e] = f2bf_s(W_proj[ci*128 + co]);
    }
}

// ---------------- per-cell multiplicity count + active mask ----------------
__global__ void kcount(const int* __restrict__ vc, unsigned* __restrict__ cnt,
                       unsigned char* __restrict__ act){
    int i = blockIdx.x*256 + threadIdx.x;
    if (i >= NVOX) return;
    const int4 c = *reinterpret_cast<const int4*>(vc + i*4);
    int cell = (c.x*Yq + c.z)*Xq + c.w;
    act[cell] = 1;
    atomicAdd(&cnt[cell], 1u);
}

// ---------------- projection + BN1 + ReLU + COALESCED scatter ----------
__global__ void __launch_bounds__(256, 2)
kproj(const float* __restrict__ vf, const int* __restrict__ vc,
      const unsigned* __restrict__ cnt,
      const short* __restrict__ wpT, const float* __restrict__ bp,
      const float* __restrict__ g1, const float* __restrict__ be1,
      const float* __restrict__ mu1, const float* __restrict__ va1,
      short* __restrict__ dbf){
    __shared__ char smem[64*200*2];     // A (bf16 stage) ∪ st (u32 pairs)
    __shared__ int cellsPk[64];         // (multi<<30) | P*8 + (xp&7)
    short*    A  = (short*)smem;
    unsigned* st = (unsigned*)smem;     // st[vx*68 + j]
    const int t = threadIdx.x;
    const int v0 = blockIdx.x * 64;

    const float4* vf4 = reinterpret_cast<const float4*>(vf);
    #pragma unroll
    for (int j = 0; j < 12; ++j){
        int i = t + j*256;
        int v = i / 48, kq = i - v*48;
        float4 x = vf4[(size_t)(v0 + v)*48 + kq];
        short4 s; s.x=f2bf_s(x.x); s.y=f2bf_s(x.y); s.z=f2bf_s(x.z); s.w=f2bf_s(x.w);
        *reinterpret_cast<short4*>(&A[v*200 + kq*4]) = s;
    }
    if (t < 64){
        int vi = v0 + t;
        int bi = vc[vi*4 + 0], yi = vc[vi*4 + 2], xi = vc[vi*4 + 3];
        unsigned cn = cnt[(bi*Yq + yi)*Xq + xi];
        int P = (bi*514 + (yi + 1))*514 + (xi + 1);
        cellsPk[t] = (P*8 + ((xi + 1) & 7)) | ((cn > 1) ? (1 << 30) : 0);
    }
    __syncthreads();

    const int w  = t >> 6;
    const int l  = t & 63;
    const int lr = l & 15;
    const int q  = l >> 4;

    const short* wp_lane = wpT + (size_t)(w*32 + lr)*192 + q*8;
    bf16x8 bb[2][6];
    #pragma unroll
    for (int n = 0; n < 2; ++n)
        #pragma unroll
        for (int kc = 0; kc < 6; ++kc)
            bb[n][kc] = *reinterpret_cast<const bf16x8*>(wp_lane + n*16*192 + kc*32);

    f32x4 acc[4][2] = {};
    #pragma unroll
    for (int kc = 0; kc < 6; ++kc){
        bf16x8 a[4];
        #pragma unroll
        for (int m = 0; m < 4; ++m)
            a[m] = *reinterpret_cast<const bf16x8*>(&A[(m*16 + lr)*200 + kc*32 + q*8]);
        #pragma unroll
        for (int m = 0; m < 4; ++m)
            #pragma unroll
            for (int n = 0; n < 2; ++n)
                acc[m][n] = __builtin_amdgcn_mfma_f32_16x16x32_bf16(a[m], bb[n][kc], acc[m][n], 0, 0, 0);
    }

    __syncthreads();
    const int odd = lr & 1;
    #pragma unroll
    for (int n = 0; n < 2; ++n){
        int c = w*32 + n*16 + lr;
        float s1  = g1[c] * rsqrtf(va1[c] + 1e-5f);
        float sh1 = be1[c] + (bp[c] - mu1[c]) * s1;
        int jj = w*16 + n*8 + (lr >> 1);
        #pragma unroll
        for (int m = 0; m < 4; ++m){
            #pragma unroll
            for (int r = 0; r < 4; ++r){
                int vx = m*16 + q*4 + r;
                float val = fmaxf(fmaf(acc[m][n][r], s1, sh1), 0.f);
                float vp  = __shfl_xor(val, 1);
                if (!odd){
                    unsigned data = (unsigned)(unsigned short)f2bf_s(val)
                                  | ((unsigned)(unsigned short)f2bf_s(vp) << 16);
                    st[vx*68 + jj] = data;
                }
            }
        }
    }
    __syncthreads();

    unsigned* dbf_u32 = reinterpret_cast<unsigned*>(dbf);
    #pragma unroll
    for (int i = 0; i < 16; ++i){
        int vv = w*16 + i;
        int pk = cellsPk[vv];
        int multi = pk >> 30;
        int P = (pk & 0x3fffffff) >> 3, xp7 = pk & 7;
        unsigned data = st[vv*68 + l];
        size_t idx = (size_t)P*64 + (((l >> 2) ^ xp7) << 2) + (l & 3);
        if (multi){
            if (data) atomic_pk_add_bf16((short*)(dbf_u32 + idx), data);
        } else {
            dbf_u32[idx] = data;
        }
    }
}

// ---------------- conv 3x3 + BN2 + ReLU + mask (R10 champion, verbatim) ----
// block: 4y x 64x x 128cout, 512 threads / 8 waves, wave tile 64pos x 64cout
// (m2n2), MFMA 32x32x16.
// A: 5-row ROTATING buffer (rows 0-4 in prologue; row 5 -> phys slot 0,
//    staged at phase 6).  B: half-tap 16KB x 4 buffers; at even phases stage
//    (p+2),(p+3).  Barrier + vmcnt(0) only at EVEN phases.
__global__ void __launch_bounds__(512, 2)
kconv(const short* __restrict__ dbf, const short* __restrict__ wTs,
      const unsigned char* __restrict__ act, const float* __restrict__ cb,
      const float* __restrict__ g2, const float* __restrict__ be2,
      const float* __restrict__ mu2, const float* __restrict__ va2,
      float* __restrict__ out){
    __shared__ short Atile[5*1056*8];    // 84,480 B
    __shared__ short Bbuf[4][1024*8];    // 4 x 16,384 B   (total 150,016 B)
    const int t = threadIdx.x;
    const int bid = (blockIdx.x & 7)*256 + (blockIdx.x >> 3);
    const int b   = bid >> 10;
    const int rem = bid & 1023;
    const int y0  = (rem >> 3) << 2;
    const int x0  = (rem & 7) << 6;

    const int w   = t >> 6, l = t & 63;
    const int yy  = w >> 1, nn = w & 1;
    const int l31 = l & 31, hi = l >> 5;
    const int wbase16 = w*64*16;

    #define STAGE_B(BUF, H) do {                                              \
        const short* gb = wTs + (size_t)((H) >> 1)*16384 + ((H) & 1)*64;      \
        _Pragma("unroll")                                                     \
        for (int j = 0; j < 2; ++j){                                          \
            int S = j*512 + t;                                                \
            const short* gp = gb + (S >> 3)*128 + (S & 7)*8;                  \
            __builtin_amdgcn_global_load_lds(                                 \
                (const __attribute__((address_space(1))) void*)gp,            \
                (__attribute__((address_space(3))) void*)                    \
                    ((char*)Bbuf[BUF] + (size_t)(j*512*16) + wbase16), 16, 0, 0); \
        }                                                                     \
    } while(0)

    // prologue: B half-taps 0,1 + A rows 0-4 (5280 slots)
    STAGE_B(0, 0);
    STAGE_B(1, 1);
    #pragma unroll
    for (int j = 0; j < 11; ++j){
        int S = j*512 + t;
        if (S < 5280){
            int r = S / 1056, s = S - r*1056;
            const short* gp = dbf + ((size_t)((b*514 + (y0 + r))*514 + x0)*16 + s)*8;
            __builtin_amdgcn_global_load_lds(
                (const __attribute__((address_space(1))) void*)gp,
                (__attribute__((address_space(3))) void*)
                    ((char*)Atile + (size_t)(j*512*16) + wbase16), 16, 0, 0);
        }
    }

    f32x16 acc[2][2] = {};
    const int bReadBase = (nn*64 + l31)*64;
    const int bXor = l31 & 7;

    #pragma unroll
    for (int p = 0; p < 18; ++p){
        if ((p & 1) == 0){
            __builtin_amdgcn_sched_barrier(0);
            asm volatile("s_waitcnt vmcnt(0)" ::: "memory");
            __builtin_amdgcn_s_barrier();
            __builtin_amdgcn_sched_barrier(0);
            if (p + 2 < 18) STAGE_B((p+2) & 3, p+2);
            if (p + 3 < 18) STAGE_B((p+3) & 3, p+3);
            if (p == 6){
                // stage padded row 5 into phys slot 0 (first read at phase 12)
                #pragma unroll
                for (int j = 0; j < 3; ++j){
                    int S = j*512 + t;
                    if (S < 1056){
                        const short* gp = dbf + ((size_t)((b*514 + (y0 + 5))*514 + x0)*16 + S)*8;
                        __builtin_amdgcn_global_load_lds(
                            (const __attribute__((address_space(1))) void*)gp,
                            (__attribute__((address_space(3))) void*)
                                ((char*)Atile + (size_t)(j*512 + w*64)*16), 16, 0, 0);
                    }
                }
            }
            __builtin_amdgcn_sched_barrier(0);
        }
        const short* Bc = Bbuf[p & 3];
        const int tap = p >> 1, hh = p & 1;
        const int ky = tap / 3, kx = tap - ky*3;
        const int row = yy + ky;
        const int rowp = (row >= 5) ? 0 : row;       // 5-row rotation
        const int p0 = l31 + kx, p1 = p0 + 32;
        const int base0 = (rowp*1056 + p0*16)*8;
        const int base1 = (rowp*1056 + p1*16)*8;
        const int pk7 = p0 & 7;
        #pragma unroll
        for (int kc = 0; kc < 4; ++kc){
            const int ks  = kc*2 + hi;
            const int q   = ((hh*8 + ks) ^ pk7) << 3;
            const int qb  = (ks ^ bXor) << 3;
            bf16x8 a0 = *reinterpret_cast<const bf16x8*>(&Atile[base0 + q]);
            bf16x8 a1 = *reinterpret_cast<const bf16x8*>(&Atile[base1 + q]);
            bf16x8 b0 = *reinterpret_cast<const bf16x8*>(&Bc[bReadBase + qb]);
            bf16x8 b1 = *reinterpret_cast<const bf16x8*>(&Bc[bReadBase + 2048 + qb]);
            acc[0][0] = __builtin_amdgcn_mfma_f32_32x32x16_bf16(a0, b0, acc[0][0], 0, 0, 0);
            acc[0][1] = __builtin_amdgcn_mfma_f32_32x32x16_bf16(a0, b1, acc[0][1], 0, 0, 0);
            acc[1][0] = __builtin_amdgcn_mfma_f32_32x32x16_bf16(a1, b0, acc[1][0], 0, 0, 0);
            acc[1][1] = __builtin_amdgcn_mfma_f32_32x32x16_bf16(a1, b1, acc[1][1], 0, 0, 0);
        }
    }
    #undef STAGE_B

    const int yg = y0 + yy;
    const size_t rowcell = (size_t)(b*Yq + yg)*Xq + x0;
    #pragma unroll
    for (int ni = 0; ni < 2; ++ni){
        int c = nn*64 + ni*32 + l31;
        float s2  = g2[c] * rsqrtf(va2[c] + 1e-3f);
        float sh2 = be2[c] + (cb[c] - mu2[c]) * s2;
        #pragma unroll
        for (int mi = 0; mi < 2; ++mi){
            #pragma unroll
            for (int r = 0; r < 16; ++r){
                int pos = mi*32 + (r & 3) + ((r >> 2) << 3) + hi*4;
                size_t cell = rowcell + pos;
                float v = act[cell] ? fmaxf(fmaf(acc[mi][ni][r], s2, sh2), 0.f) : 0.f;
                out[cell*128 + c] = v;
            }
        }
    }
}

extern "C" void kernel_launch(void* const* d_in, const int* in_sizes, int n_in,
                              void* d_out, int out_size, void* d_ws, size_t ws_size,
                              hipStream_t stream){
    const float* vf  = (const float*)d_in[0];
    const int*   vc  = (const int*)  d_in[1];
    const float* Wp  = (const float*)d_in[2];
    const float* bp  = (const float*)d_in[3];
    const float* g1  = (const float*)d_in[4];
    const float* be1 = (const float*)d_in[5];
    const float* mu1 = (const float*)d_in[6];
    const float* va1 = (const float*)d_in[7];
    const float* cw  = (const float*)d_in[8];
    const float* cb  = (const float*)d_in[9];
    const float* g2  = (const float*)d_in[10];
    const float* be2 = (const float*)d_in[11];
    const float* mu2 = (const float*)d_in[12];
    const float* va2 = (const float*)d_in[13];
    float* out = (float*)d_out;
    char* ws = (char*)d_ws;

    // ws layout (bytes):
    //   dbf bf16 [2][514][514][128] : 135,268,352 @ 0   (padded, pre-swizzled)
    //   act  u8  [2][512][512]      :     524,288 @ 135,268,352
    //   wTs  bf16 [9][128][128]     :     294,912 @ 135,792,640  (pre-swizzled)
    //   wpT  bf16 [128][192]        :      49,152 @ 136,087,552
    //   cnt  u32 [2][512][512]      :   2,097,152 @ 136,136,704  (end 138,233,856)
    if (ws_size < 138233856ull) return;
    short* dbf = (short*)ws;
    unsigned char* act = (unsigned char*)(ws + 135268352);
    short* wTs = (short*)(ws + 135792640);
    short* wpT = (short*)(ws + 136087552);
    unsigned* cnt = (unsigned*)(ws + 136136704);

    hipMemsetAsync(dbf, 0, 135268352, stream);
    hipMemsetAsync(act, 0, 524288, stream);
    hipMemsetAsync(cnt, 0, 2097152, stream);
    kprep<<<672, 256, 0, stream>>>(cw, Wp, wTs, wpT);
    kcount<<<1563, 256, 0, stream>>>(vc, cnt, act);
    kproj<<<6250, 256, 0, stream>>>(vf, vc, cnt, wpT, bp, g1, be1, mu1, va1, dbf);
    kconv<<<2048, 512, 0, stream>>>(dbf, wTs, act, cb, g2, be2, mu2, va2, out);
}

// Round 19
// 354.201 us; speedup vs baseline: 1.6427x; 1.0115x over previous
//
#include <hip/hip_runtime.h>

#define Bq 2
#define Yq 512
#define Xq 512
#define NVOX 400000

typedef __bf16 bf16x8 __attribute__((ext_vector_type(8)));
typedef float f32x4 __attribute__((ext_vector_type(4)));
typedef float f32x16 __attribute__((ext_vector_type(16)));
typedef short s16x8 __attribute__((ext_vector_type(8)));
typedef short s16x2 __attribute__((ext_vector_type(2)));

__device__ __forceinline__ short f2bf_s(float f){
    return __builtin_bit_cast(short, static_cast<__bf16>(f));
}

__device__ __forceinline__ void atomic_pk_add_bf16(short* addr, unsigned data){
#if __has_builtin(__builtin_amdgcn_global_atomic_fadd_v2bf16)
    s16x2 v; v[0] = (short)(data & 0xffff); v[1] = (short)(data >> 16);
    __builtin_amdgcn_global_atomic_fadd_v2bf16(
        (__attribute__((address_space(1))) s16x2*)addr, v);
#else
    asm volatile("global_atomic_pk_add_bf16 %0, %1, off"
                 :: "v"(addr), "v"(data) : "memory");
#endif
}

// ---------------- fused: weight transpose/convert + per-cell count ----------
// blocks [0,672): wTs/wpT prep.  blocks [672,2235): voxel count + act mask.
__global__ void kinit(const float* __restrict__ conv_w, const float* __restrict__ W_proj,
                      short* __restrict__ wTs, short* __restrict__ wpT,
                      const int* __restrict__ vc, unsigned* __restrict__ cnt,
                      unsigned char* __restrict__ act){
    const int bx = blockIdx.x;
    if (bx < 672){
        int tid = bx*256 + threadIdx.x;
        if (tid < 9*128*128){
            int tap = tid >> 14; int r = tid & 16383; int co = r >> 7; int ci = r & 127;
            int g = ci >> 3, e = ci & 7;
            wTs[tap*16384 + co*128 + (((g & 8) | ((g & 7) ^ (co & 7))) << 3) + e] =
                f2bf_s(conv_w[tap*16384 + ci*128 + co]);
        }
        int e = tid - 9*128*128;
        if (e >= 0 && e < 128*192){
            int co = e / 192; int ci = e - co*192;
            wpT[e] = f2bf_s(W_proj[ci*128 + co]);
        }
    } else {
        int i = (bx - 672)*256 + threadIdx.x;
        if (i < NVOX){
            const int4 c = *reinterpret_cast<const int4*>(vc + i*4);
            int cell = (c.x*Yq + c.z)*Xq + c.w;
            act[cell] = 1;
            atomicAdd(&cnt[cell], 1u);
        }
    }
}

// ---------------- projection + BN1 + ReLU + COALESCED scatter (unchanged) --
__global__ void __launch_bounds__(256, 2)
kproj(const float* __restrict__ vf, const int* __restrict__ vc,
      const unsigned* __restrict__ cnt,
      const short* __restrict__ wpT, const float* __restrict__ bp,
      const float* __restrict__ g1, const float* __restrict__ be1,
      const float* __restrict__ mu1, const float* __restrict__ va1,
      short* __restrict__ dbf){
    __shared__ char smem[64*200*2];     // A (bf16 stage) ∪ st (u32 pairs)
    __shared__ int cellsPk[64];         // (multi<<30) | P*8 + (xp&7)
    short*    A  = (short*)smem;
    unsigned* st = (unsigned*)smem;     // st[vx*68 + j]
    const int t = threadIdx.x;
    const int v0 = blockIdx.x * 64;

    const float4* vf4 = reinterpret_cast<const float4*>(vf);
    #pragma unroll
    for (int j = 0; j < 12; ++j){
        int i = t + j*256;
        int v = i / 48, kq = i - v*48;
        float4 x = vf4[(size_t)(v0 + v)*48 + kq];
        short4 s; s.x=f2bf_s(x.x); s.y=f2bf_s(x.y); s.z=f2bf_s(x.z); s.w=f2bf_s(x.w);
        *reinterpret_cast<short4*>(&A[v*200 + kq*4]) = s;
    }
    if (t < 64){
        int vi = v0 + t;
        int bi = vc[vi*4 + 0], yi = vc[vi*4 + 2], xi = vc[vi*4 + 3];
        unsigned cn = cnt[(bi*Yq + yi)*Xq + xi];
        int P = (bi*514 + (yi + 1))*514 + (xi + 1);
        cellsPk[t] = (P*8 + ((xi + 1) & 7)) | ((cn > 1) ? (1 << 30) : 0);
    }
    __syncthreads();

    const int w  = t >> 6;
    const int l  = t & 63;
    const int lr = l & 15;
    const int q  = l >> 4;

    const short* wp_lane = wpT + (size_t)(w*32 + lr)*192 + q*8;
    bf16x8 bb[2][6];
    #pragma unroll
    for (int n = 0; n < 2; ++n)
        #pragma unroll
        for (int kc = 0; kc < 6; ++kc)
            bb[n][kc] = *reinterpret_cast<const bf16x8*>(wp_lane + n*16*192 + kc*32);

    f32x4 acc[4][2] = {};
    #pragma unroll
    for (int kc = 0; kc < 6; ++kc){
        bf16x8 a[4];
        #pragma unroll
        for (int m = 0; m < 4; ++m)
            a[m] = *reinterpret_cast<const bf16x8*>(&A[(m*16 + lr)*200 + kc*32 + q*8]);
        #pragma unroll
        for (int m = 0; m < 4; ++m)
            #pragma unroll
            for (int n = 0; n < 2; ++n)
                acc[m][n] = __builtin_amdgcn_mfma_f32_16x16x32_bf16(a[m], bb[n][kc], acc[m][n], 0, 0, 0);
    }

    __syncthreads();
    const int odd = lr & 1;
    #pragma unroll
    for (int n = 0; n < 2; ++n){
        int c = w*32 + n*16 + lr;
        float s1  = g1[c] * rsqrtf(va1[c] + 1e-5f);
        float sh1 = be1[c] + (bp[c] - mu1[c]) * s1;
        int jj = w*16 + n*8 + (lr >> 1);
        #pragma unroll
        for (int m = 0; m < 4; ++m){
            #pragma unroll
            for (int r = 0; r < 4; ++r){
                int vx = m*16 + q*4 + r;
                float val = fmaxf(fmaf(acc[m][n][r], s1, sh1), 0.f);
                float vp  = __shfl_xor(val, 1);
                if (!odd){
                    unsigned data = (unsigned)(unsigned short)f2bf_s(val)
                                  | ((unsigned)(unsigned short)f2bf_s(vp) << 16);
                    st[vx*68 + jj] = data;
                }
            }
        }
    }
    __syncthreads();

    unsigned* dbf_u32 = reinterpret_cast<unsigned*>(dbf);
    #pragma unroll
    for (int i = 0; i < 16; ++i){
        int vv = w*16 + i;
        int pk = cellsPk[vv];
        int multi = pk >> 30;
        int P = (pk & 0x3fffffff) >> 3, xp7 = pk & 7;
        unsigned data = st[vv*68 + l];
        size_t idx = (size_t)P*64 + (((l >> 2) ^ xp7) << 2) + (l & 3);
        if (multi){
            if (data) atomic_pk_add_bf16((short*)(dbf_u32 + idx), data);
        } else {
            dbf_u32[idx] = data;
        }
    }
}

// ---------------- conv 3x3 + BN2 + ReLU + mask — persistent y-walk ----------
// block: 16-output-row strip x 64x x 128cout; 4 groups of 4 rows, each group
// = R10's proven 18-phase loop (8 waves m2n2, MFMA 32x32x16).
// A: mod-5 rotating ring over block-local padded rows R in [0,17]:
//   prologue R0-4; group g stages R=4g+4@p0(g>=1), 4g+5@p6, 4g+6@p12 (hidden),
//   R=4g+3 at the group boundary (after a barrier; drained by p0's vmcnt).
// B: 4 half-tap buffers continue across groups: buf=(2g+p)&3, src h=(p+2)%18.
__global__ void __launch_bounds__(512, 2)
kconv(const short* __restrict__ dbf, const short* __restrict__ wTs,
      const unsigned char* __restrict__ act, const float* __restrict__ cb,
      const float* __restrict__ g2, const float* __restrict__ be2,
      const float* __restrict__ mu2, const float* __restrict__ va2,
      float* __restrict__ out){
    __shared__ short Atile[5*1056*8];    // 84,480 B (5-slot ring)
    __shared__ short Bbuf[4][1024*8];    // 4 x 16,384 B  (total 150,016 B)
    const int t = threadIdx.x;
    // 512 blocks: bijective XCD swizzle, 64/XCD
    const int bid = (blockIdx.x & 7)*64 + (blockIdx.x >> 3);
    const int b   = bid >> 8;
    const int rem = bid & 255;
    const int y0  = (rem >> 3) << 4;     // strip of 16 output rows
    const int x0  = (rem & 7) << 6;

    const int w   = t >> 6, l = t & 63;
    const int yy  = w >> 1, nn = w & 1;
    const int l31 = l & 31, hi = l >> 5;
    const int wbase16 = w*64*16;

    #define STAGE_B(BUF, H) do {                                              \
        const short* gb = wTs + (size_t)((H) >> 1)*16384 + ((H) & 1)*64;      \
        _Pragma("unroll")                                                     \
        for (int j = 0; j < 2; ++j){                                          \
            int S = j*512 + t;                                                \
            const short* gp = gb + (S >> 3)*128 + (S & 7)*8;                  \
            __builtin_amdgcn_global_load_lds(                                 \
                (const __attribute__((address_space(1))) void*)gp,            \
                (__attribute__((address_space(3))) void*)                    \
                    ((char*)Bbuf[BUF] + (size_t)(j*512*16) + wbase16), 16, 0, 0); \
        }                                                                     \
    } while(0)

    // stage block-local padded row R -> ring slot R%5
    #define STAGE_A(R) do {                                                   \
        const int slot_ = (R) % 5;                                            \
        _Pragma("unroll")                                                     \
        for (int j = 0; j < 3; ++j){                                          \
            int S = j*512 + t;                                                \
            if (S < 1056){                                                    \
                const short* gp = dbf +                                       \
                    ((size_t)((b*514 + (y0 + (R)))*514 + x0)*16 + S)*8;       \
                __builtin_amdgcn_global_load_lds(                             \
                    (const __attribute__((address_space(1))) void*)gp,        \
                    (__attribute__((address_space(3))) void*)                \
                        ((char*)Atile + (size_t)(slot_*1056 + j*512 + w*64)*16), \
                    16, 0, 0);                                                \
            }                                                                 \
        }                                                                     \
    } while(0)

    // prologue: B half-taps 0,1 + A rows 0-4
    STAGE_B(0, 0);
    STAGE_B(1, 1);
    STAGE_A(0); STAGE_A(1); STAGE_A(2); STAGE_A(3); STAGE_A(4);

    const int bReadBase = (nn*64 + l31)*64;
    const int bXor = l31 & 7;

    // hoisted BN2 constants (group-invariant)
    float s2c[2], sh2c[2];
    #pragma unroll
    for (int ni = 0; ni < 2; ++ni){
        int c = nn*64 + ni*32 + l31;
        s2c[ni]  = g2[c] * rsqrtf(va2[c] + 1e-3f);
        sh2c[ni] = be2[c] + (cb[c] - mu2[c]) * s2c[ni];
    }

    #pragma unroll 1
    for (int g = 0; g < 4; ++g){
        f32x16 acc[2][2] = {};
        if (g >= 1){
            // boundary: all group g-1 LDS reads done, then stage R=4g+3
            __builtin_amdgcn_sched_barrier(0);
            __builtin_amdgcn_s_barrier();
            __builtin_amdgcn_sched_barrier(0);
            STAGE_A(4*g + 3);   // drained by p==0's vmcnt(0) below
        }
        #pragma unroll
        for (int p = 0; p < 18; ++p){
            if ((p & 1) == 0){
                __builtin_amdgcn_sched_barrier(0);
                asm volatile("s_waitcnt vmcnt(0)" ::: "memory");
                __builtin_amdgcn_s_barrier();
                __builtin_amdgcn_sched_barrier(0);
                const int P = g*18 + p;
                if (P + 2 < 72) STAGE_B((2*g + p + 2) & 3, (p + 2) % 18);
                if (P + 3 < 72) STAGE_B((2*g + p + 3) & 3, (p + 3) % 18);
                if (p == 0 && g >= 1)           STAGE_A(4*g + 4);
                if (p == 6)                     STAGE_A(4*g + 5);
                if (p == 12 && (4*g + 6) <= 17) STAGE_A(4*g + 6);
                __builtin_amdgcn_sched_barrier(0);
            }
            const short* Bc = Bbuf[(2*g + p) & 3];
            const int tap = p >> 1, hh = p & 1;
            const int ky = tap / 3, kx = tap - ky*3;
            const int R  = 4*g + yy + ky;
            const int rowp = R % 5;
            const int p0 = l31 + kx, p1 = p0 + 32;
            const int base0 = (rowp*1056 + p0*16)*8;
            const int base1 = (rowp*1056 + p1*16)*8;
            const int pk7 = p0 & 7;
            #pragma unroll
            for (int kc = 0; kc < 4; ++kc){
                const int ks  = kc*2 + hi;
                const int q   = ((hh*8 + ks) ^ pk7) << 3;
                const int qb  = (ks ^ bXor) << 3;
                bf16x8 a0 = *reinterpret_cast<const bf16x8*>(&Atile[base0 + q]);
                bf16x8 a1 = *reinterpret_cast<const bf16x8*>(&Atile[base1 + q]);
                bf16x8 b0 = *reinterpret_cast<const bf16x8*>(&Bc[bReadBase + qb]);
                bf16x8 b1 = *reinterpret_cast<const bf16x8*>(&Bc[bReadBase + 2048 + qb]);
                acc[0][0] = __builtin_amdgcn_mfma_f32_32x32x16_bf16(a0, b0, acc[0][0], 0, 0, 0);
                acc[0][1] = __builtin_amdgcn_mfma_f32_32x32x16_bf16(a0, b1, acc[0][1], 0, 0, 0);
                acc[1][0] = __builtin_amdgcn_mfma_f32_32x32x16_bf16(a1, b0, acc[1][0], 0, 0, 0);
                acc[1][1] = __builtin_amdgcn_mfma_f32_32x32x16_bf16(a1, b1, acc[1][1], 0, 0, 0);
            }
        }
        // epilogue for group g: BN2 + ReLU + mask
        const int yg = y0 + 4*g + yy;
        const size_t rowcell = (size_t)(b*Yq + yg)*Xq + x0;
        #pragma unroll
        for (int ni = 0; ni < 2; ++ni){
            int c = nn*64 + ni*32 + l31;
            #pragma unroll
            for (int mi = 0; mi < 2; ++mi){
                #pragma unroll
                for (int r = 0; r < 16; ++r){
                    int pos = mi*32 + (r & 3) + ((r >> 2) << 3) + hi*4;
                    size_t cell = rowcell + pos;
                    float v = act[cell] ? fmaxf(fmaf(acc[mi][ni][r], s2c[ni], sh2c[ni]), 0.f) : 0.f;
                    out[cell*128 + c] = v;
                }
            }
        }
    }
    #undef STAGE_A
    #undef STAGE_B
}

extern "C" void kernel_launch(void* const* d_in, const int* in_sizes, int n_in,
                              void* d_out, int out_size, void* d_ws, size_t ws_size,
                              hipStream_t stream){
    const float* vf  = (const float*)d_in[0];
    const int*   vc  = (const int*)  d_in[1];
    const float* Wp  = (const float*)d_in[2];
    const float* bp  = (const float*)d_in[3];
    const float* g1  = (const float*)d_in[4];
    const float* be1 = (const float*)d_in[5];
    const float* mu1 = (const float*)d_in[6];
    const float* va1 = (const float*)d_in[7];
    const float* cw  = (const float*)d_in[8];
    const float* cb  = (const float*)d_in[9];
    const float* g2  = (const float*)d_in[10];
    const float* be2 = (const float*)d_in[11];
    const float* mu2 = (const float*)d_in[12];
    const float* va2 = (const float*)d_in[13];
    float* out = (float*)d_out;
    char* ws = (char*)d_ws;

    // ws layout (bytes):
    //   dbf bf16 [2][514][514][128] : 135,268,352 @ 0   (padded, pre-swizzled)
    //   act  u8  [2][512][512]      :     524,288 @ 135,268,352
    //   wTs  bf16 [9][128][128]     :     294,912 @ 135,792,640  (pre-swizzled)
    //   wpT  bf16 [128][192]        :      49,152 @ 136,087,552
    //   cnt  u32 [2][512][512]      :   2,097,152 @ 136,136,704  (end 138,233,856)
    if (ws_size < 138233856ull) return;
    short* dbf = (short*)ws;
    unsigned char* act = (unsigned char*)(ws + 135268352);
    short* wTs = (short*)(ws + 135792640);
    short* wpT = (short*)(ws + 136087552);
    unsigned* cnt = (unsigned*)(ws + 136136704);

    hipMemsetAsync(dbf, 0, 135268352, stream);
    hipMemsetAsync(act, 0, 524288, stream);
    hipMemsetAsync(cnt, 0, 2097152, stream);
    kinit<<<2235, 256, 0, stream>>>(cw, Wp, wTs, wpT, vc, cnt, act);
    kproj<<<6250, 256, 0, stream>>>(vf, vc, cnt, wpT, bp, g1, be1, mu1, va1, dbf);
    kconv<<<512, 512, 0, stream>>>(dbf, wTs, act, cb, g2, be2, mu2, va2, out);
}

// Round 20
// 349.912 us; speedup vs baseline: 1.6629x; 1.0123x over previous
//
#include <hip/hip_runtime.h>

#define Bq 2
#define Yq 512
#define Xq 512
#define NVOX 400000

typedef __bf16 bf16x8 __attribute__((ext_vector_type(8)));
typedef float f32x4 __attribute__((ext_vector_type(4)));
typedef float f32x16 __attribute__((ext_vector_type(16)));
typedef short s16x8 __attribute__((ext_vector_type(8)));
typedef short s16x2 __attribute__((ext_vector_type(2)));

__device__ __forceinline__ short f2bf_s(float f){
    return __builtin_bit_cast(short, static_cast<__bf16>(f));
}

__device__ __forceinline__ void atomic_pk_add_bf16(short* addr, unsigned data){
#if __has_builtin(__builtin_amdgcn_global_atomic_fadd_v2bf16)
    s16x2 v; v[0] = (short)(data & 0xffff); v[1] = (short)(data >> 16);
    __builtin_amdgcn_global_atomic_fadd_v2bf16(
        (__attribute__((address_space(1))) s16x2*)addr, v);
#else
    asm volatile("global_atomic_pk_add_bf16 %0, %1, off"
                 :: "v"(addr), "v"(data) : "memory");
#endif
}

// ---- fused: weight transpose/convert + per-cell count + dbf zero-fill ------
// blocks [0,672): wTs/wpT prep.  [672,2235): voxel count + act mask.
// [2235,4300): zero dbf (135,268,352 B = 8,454,272 uint4 slots) — overlaps
// the (independent) prep/count work, replacing a serial 135MB memset.
__global__ void kinit(const float* __restrict__ conv_w, const float* __restrict__ W_proj,
                      short* __restrict__ wTs, short* __restrict__ wpT,
                      const int* __restrict__ vc, unsigned* __restrict__ cnt,
                      unsigned char* __restrict__ act, uint4* __restrict__ dbf16){
    const int bx = blockIdx.x;
    if (bx < 672){
        int tid = bx*256 + threadIdx.x;
        if (tid < 9*128*128){
            int tap = tid >> 14; int r = tid & 16383; int co = r >> 7; int ci = r & 127;
            int g = ci >> 3, e = ci & 7;
            wTs[tap*16384 + co*128 + (((g & 8) | ((g & 7) ^ (co & 7))) << 3) + e] =
                f2bf_s(conv_w[tap*16384 + ci*128 + co]);
        }
        int e = tid - 9*128*128;
        if (e >= 0 && e < 128*192){
            int co = e / 192; int ci = e - co*192;
            wpT[e] = f2bf_s(W_proj[ci*128 + co]);
        }
    } else if (bx < 2235){
        int i = (bx - 672)*256 + threadIdx.x;
        if (i < NVOX){
            const int4 c = *reinterpret_cast<const int4*>(vc + i*4);
            int cell = (c.x*Yq + c.z)*Xq + c.w;
            act[cell] = 1;
            atomicAdd(&cnt[cell], 1u);
        }
    } else {
        const uint4 z = {0u,0u,0u,0u};
        const size_t b0 = (size_t)(bx - 2235)*4096 + threadIdx.x;
        #pragma unroll
        for (int j = 0; j < 16; ++j){
            size_t s = b0 + (size_t)j*256;
            if (s < 8454272ull) dbf16[s] = z;
        }
    }
}

// ---------------- projection + BN1 + ReLU + COALESCED scatter (unchanged) --
__global__ void __launch_bounds__(256, 2)
kproj(const float* __restrict__ vf, const int* __restrict__ vc,
      const unsigned* __restrict__ cnt,
      const short* __restrict__ wpT, const float* __restrict__ bp,
      const float* __restrict__ g1, const float* __restrict__ be1,
      const float* __restrict__ mu1, const float* __restrict__ va1,
      short* __restrict__ dbf){
    __shared__ char smem[64*200*2];     // A (bf16 stage) ∪ st (u32 pairs)
    __shared__ int cellsPk[64];         // (multi<<30) | P*8 + (xp&7)
    short*    A  = (short*)smem;
    unsigned* st = (unsigned*)smem;     // st[vx*68 + j]
    const int t = threadIdx.x;
    const int v0 = blockIdx.x * 64;

    const float4* vf4 = reinterpret_cast<const float4*>(vf);
    #pragma unroll
    for (int j = 0; j < 12; ++j){
        int i = t + j*256;
        int v = i / 48, kq = i - v*48;
        float4 x = vf4[(size_t)(v0 + v)*48 + kq];
        short4 s; s.x=f2bf_s(x.x); s.y=f2bf_s(x.y); s.z=f2bf_s(x.z); s.w=f2bf_s(x.w);
        *reinterpret_cast<short4*>(&A[v*200 + kq*4]) = s;
    }
    if (t < 64){
        int vi = v0 + t;
        int bi = vc[vi*4 + 0], yi = vc[vi*4 + 2], xi = vc[vi*4 + 3];
        unsigned cn = cnt[(bi*Yq + yi)*Xq + xi];
        int P = (bi*514 + (yi + 1))*514 + (xi + 1);
        cellsPk[t] = (P*8 + ((xi + 1) & 7)) | ((cn > 1) ? (1 << 30) : 0);
    }
    __syncthreads();

    const int w  = t >> 6;
    const int l  = t & 63;
    const int lr = l & 15;
    const int q  = l >> 4;

    const short* wp_lane = wpT + (size_t)(w*32 + lr)*192 + q*8;
    bf16x8 bb[2][6];
    #pragma unroll
    for (int n = 0; n < 2; ++n)
        #pragma unroll
        for (int kc = 0; kc < 6; ++kc)
            bb[n][kc] = *reinterpret_cast<const bf16x8*>(wp_lane + n*16*192 + kc*32);

    f32x4 acc[4][2] = {};
    #pragma unroll
    for (int kc = 0; kc < 6; ++kc){
        bf16x8 a[4];
        #pragma unroll
        for (int m = 0; m < 4; ++m)
            a[m] = *reinterpret_cast<const bf16x8*>(&A[(m*16 + lr)*200 + kc*32 + q*8]);
        #pragma unroll
        for (int m = 0; m < 4; ++m)
            #pragma unroll
            for (int n = 0; n < 2; ++n)
                acc[m][n] = __builtin_amdgcn_mfma_f32_16x16x32_bf16(a[m], bb[n][kc], acc[m][n], 0, 0, 0);
    }

    __syncthreads();
    const int odd = lr & 1;
    #pragma unroll
    for (int n = 0; n < 2; ++n){
        int c = w*32 + n*16 + lr;
        float s1  = g1[c] * rsqrtf(va1[c] + 1e-5f);
        float sh1 = be1[c] + (bp[c] - mu1[c]) * s1;
        int jj = w*16 + n*8 + (lr >> 1);
        #pragma unroll
        for (int m = 0; m < 4; ++m){
            #pragma unroll
            for (int r = 0; r < 4; ++r){
                int vx = m*16 + q*4 + r;
                float val = fmaxf(fmaf(acc[m][n][r], s1, sh1), 0.f);
                float vp  = __shfl_xor(val, 1);
                if (!odd){
                    unsigned data = (unsigned)(unsigned short)f2bf_s(val)
                                  | ((unsigned)(unsigned short)f2bf_s(vp) << 16);
                    st[vx*68 + jj] = data;
                }
            }
        }
    }
    __syncthreads();

    unsigned* dbf_u32 = reinterpret_cast<unsigned*>(dbf);
    #pragma unroll
    for (int i = 0; i < 16; ++i){
        int vv = w*16 + i;
        int pk = cellsPk[vv];
        int multi = pk >> 30;
        int P = (pk & 0x3fffffff) >> 3, xp7 = pk & 7;
        unsigned data = st[vv*68 + l];
        size_t idx = (size_t)P*64 + (((l >> 2) ^ xp7) << 2) + (l & 3);
        if (multi){
            if (data) atomic_pk_add_bf16((short*)(dbf_u32 + idx), data);
        } else {
            dbf_u32[idx] = data;
        }
    }
}

// ---------------- conv 3x3 + BN2 + ReLU + mask — persistent y-walk (R19) ----
__global__ void __launch_bounds__(512, 2)
kconv(const short* __restrict__ dbf, const short* __restrict__ wTs,
      const unsigned char* __restrict__ act, const float* __restrict__ cb,
      const float* __restrict__ g2, const float* __restrict__ be2,
      const float* __restrict__ mu2, const float* __restrict__ va2,
      float* __restrict__ out){
    __shared__ short Atile[5*1056*8];    // 84,480 B (5-slot ring)
    __shared__ short Bbuf[4][1024*8];    // 4 x 16,384 B  (total 150,016 B)
    const int t = threadIdx.x;
    const int bid = (blockIdx.x & 7)*64 + (blockIdx.x >> 3);
    const int b   = bid >> 8;
    const int rem = bid & 255;
    const int y0  = (rem >> 3) << 4;     // strip of 16 output rows
    const int x0  = (rem & 7) << 6;

    const int w   = t >> 6, l = t & 63;
    const int yy  = w >> 1, nn = w & 1;
    const int l31 = l & 31, hi = l >> 5;
    const int wbase16 = w*64*16;

    #define STAGE_B(BUF, H) do {                                              \
        const short* gb = wTs + (size_t)((H) >> 1)*16384 + ((H) & 1)*64;      \
        _Pragma("unroll")                                                     \
        for (int j = 0; j < 2; ++j){                                          \
            int S = j*512 + t;                                                \
            const short* gp = gb + (S >> 3)*128 + (S & 7)*8;                  \
            __builtin_amdgcn_global_load_lds(                                 \
                (const __attribute__((address_space(1))) void*)gp,            \
                (__attribute__((address_space(3))) void*)                    \
                    ((char*)Bbuf[BUF] + (size_t)(j*512*16) + wbase16), 16, 0, 0); \
        }                                                                     \
    } while(0)

    #define STAGE_A(R) do {                                                   \
        const int slot_ = (R) % 5;                                            \
        _Pragma("unroll")                                                     \
        for (int j = 0; j < 3; ++j){                                          \
            int S = j*512 + t;                                                \
            if (S < 1056){                                                    \
                const short* gp = dbf +                                       \
                    ((size_t)((b*514 + (y0 + (R)))*514 + x0)*16 + S)*8;       \
                __builtin_amdgcn_global_load_lds(                             \
                    (const __attribute__((address_space(1))) void*)gp,        \
                    (__attribute__((address_space(3))) void*)                \
                        ((char*)Atile + (size_t)(slot_*1056 + j*512 + w*64)*16), \
                    16, 0, 0);                                                \
            }                                                                 \
        }                                                                     \
    } while(0)

    STAGE_B(0, 0);
    STAGE_B(1, 1);
    STAGE_A(0); STAGE_A(1); STAGE_A(2); STAGE_A(3); STAGE_A(4);

    const int bReadBase = (nn*64 + l31)*64;
    const int bXor = l31 & 7;

    float s2c[2], sh2c[2];
    #pragma unroll
    for (int ni = 0; ni < 2; ++ni){
        int c = nn*64 + ni*32 + l31;
        s2c[ni]  = g2[c] * rsqrtf(va2[c] + 1e-3f);
        sh2c[ni] = be2[c] + (cb[c] - mu2[c]) * s2c[ni];
    }

    #pragma unroll 1
    for (int g = 0; g < 4; ++g){
        f32x16 acc[2][2] = {};
        if (g >= 1){
            __builtin_amdgcn_sched_barrier(0);
            __builtin_amdgcn_s_barrier();
            __builtin_amdgcn_sched_barrier(0);
            STAGE_A(4*g + 3);
        }
        #pragma unroll
        for (int p = 0; p < 18; ++p){
            if ((p & 1) == 0){
                __builtin_amdgcn_sched_barrier(0);
                asm volatile("s_waitcnt vmcnt(0)" ::: "memory");
                __builtin_amdgcn_s_barrier();
                __builtin_amdgcn_sched_barrier(0);
                const int P = g*18 + p;
                if (P + 2 < 72) STAGE_B((2*g + p + 2) & 3, (p + 2) % 18);
                if (P + 3 < 72) STAGE_B((2*g + p + 3) & 3, (p + 3) % 18);
                if (p == 0 && g >= 1)           STAGE_A(4*g + 4);
                if (p == 6)                     STAGE_A(4*g + 5);
                if (p == 12 && (4*g + 6) <= 17) STAGE_A(4*g + 6);
                __builtin_amdgcn_sched_barrier(0);
            }
            const short* Bc = Bbuf[(2*g + p) & 3];
            const int tap = p >> 1, hh = p & 1;
            const int ky = tap / 3, kx = tap - ky*3;
            const int R  = 4*g + yy + ky;
            const int rowp = R % 5;
            const int p0 = l31 + kx, p1 = p0 + 32;
            const int base0 = (rowp*1056 + p0*16)*8;
            const int base1 = (rowp*1056 + p1*16)*8;
            const int pk7 = p0 & 7;
            #pragma unroll
            for (int kc = 0; kc < 4; ++kc){
                const int ks  = kc*2 + hi;
                const int q   = ((hh*8 + ks) ^ pk7) << 3;
                const int qb  = (ks ^ bXor) << 3;
                bf16x8 a0 = *reinterpret_cast<const bf16x8*>(&Atile[base0 + q]);
                bf16x8 a1 = *reinterpret_cast<const bf16x8*>(&Atile[base1 + q]);
                bf16x8 b0 = *reinterpret_cast<const bf16x8*>(&Bc[bReadBase + qb]);
                bf16x8 b1 = *reinterpret_cast<const bf16x8*>(&Bc[bReadBase + 2048 + qb]);
                acc[0][0] = __builtin_amdgcn_mfma_f32_32x32x16_bf16(a0, b0, acc[0][0], 0, 0, 0);
                acc[0][1] = __builtin_amdgcn_mfma_f32_32x32x16_bf16(a0, b1, acc[0][1], 0, 0, 0);
                acc[1][0] = __builtin_amdgcn_mfma_f32_32x32x16_bf16(a1, b0, acc[1][0], 0, 0, 0);
                acc[1][1] = __builtin_amdgcn_mfma_f32_32x32x16_bf16(a1, b1, acc[1][1], 0, 0, 0);
            }
        }
        const int yg = y0 + 4*g + yy;
        const size_t rowcell = (size_t)(b*Yq + yg)*Xq + x0;
        #pragma unroll
        for (int ni = 0; ni < 2; ++ni){
            int c = nn*64 + ni*32 + l31;
            #pragma unroll
            for (int mi = 0; mi < 2; ++mi){
                #pragma unroll
                for (int r = 0; r < 16; ++r){
                    int pos = mi*32 + (r & 3) + ((r >> 2) << 3) + hi*4;
                    size_t cell = rowcell + pos;
                    float v = act[cell] ? fmaxf(fmaf(acc[mi][ni][r], s2c[ni], sh2c[ni]), 0.f) : 0.f;
                    out[cell*128 + c] = v;
                }
            }
        }
    }
    #undef STAGE_A
    #undef STAGE_B
}

extern "C" void kernel_launch(void* const* d_in, const int* in_sizes, int n_in,
                              void* d_out, int out_size, void* d_ws, size_t ws_size,
                              hipStream_t stream){
    const float* vf  = (const float*)d_in[0];
    const int*   vc  = (const int*)  d_in[1];
    const float* Wp  = (const float*)d_in[2];
    const float* bp  = (const float*)d_in[3];
    const float* g1  = (const float*)d_in[4];
    const float* be1 = (const float*)d_in[5];
    const float* mu1 = (const float*)d_in[6];
    const float* va1 = (const float*)d_in[7];
    const float* cw  = (const float*)d_in[8];
    const float* cb  = (const float*)d_in[9];
    const float* g2  = (const float*)d_in[10];
    const float* be2 = (const float*)d_in[11];
    const float* mu2 = (const float*)d_in[12];
    const float* va2 = (const float*)d_in[13];
    float* out = (float*)d_out;
    char* ws = (char*)d_ws;

    // ws layout (bytes):
    //   dbf bf16 [2][514][514][128] : 135,268,352 @ 0   (padded, pre-swizzled)
    //   act  u8  [2][512][512]      :     524,288 @ 135,268,352
    //   wTs  bf16 [9][128][128]     :     294,912 @ 135,792,640  (pre-swizzled)
    //   wpT  bf16 [128][192]        :      49,152 @ 136,087,552
    //   cnt  u32 [2][512][512]      :   2,097,152 @ 136,136,704  (end 138,233,856)
    if (ws_size < 138233856ull) return;
    short* dbf = (short*)ws;
    unsigned char* act = (unsigned char*)(ws + 135268352);
    short* wTs = (short*)(ws + 135792640);
    short* wpT = (short*)(ws + 136087552);
    unsigned* cnt = (unsigned*)(ws + 136136704);

    hipMemsetAsync(act, 0, 524288, stream);
    hipMemsetAsync(cnt, 0, 2097152, stream);
    kinit<<<4300, 256, 0, stream>>>(cw, Wp, wTs, wpT, vc, cnt, act, (uint4*)dbf);
    kproj<<<6250, 256, 0, stream>>>(vf, vc, cnt, wpT, bp, g1, be1, mu1, va1, dbf);
    kconv<<<512, 512, 0, stream>>>(dbf, wTs, act, cb, g2, be2, mu2, va2, out);
}